// Round 1
// baseline (1573.159 us; speedup 1.0000x reference)
//
#include <hip/hip_runtime.h>
#include <math.h>

#define DMODEL 128
#define NHEAD 8
#define HEADD 16
#define NLAYER 2
#define FFDIM 512
#define FFCHUNK 12544   // rows per FFN chunk (multiple of 64)

// ---------------------------------------------------------------------------
// LayerNorm: one wave (64 lanes) per row of 128; float2 per lane.
// ---------------------------------------------------------------------------
__global__ __launch_bounds__(256)
void ln_kernel(const float* __restrict__ x, const float* __restrict__ g,
               const float* __restrict__ b, float* __restrict__ out, int n)
{
    int wave = threadIdx.x >> 6;
    int lane = threadIdx.x & 63;
    int row  = blockIdx.x * 4 + wave;
    if (row >= n) return;
    float2 xv = *(const float2*)(x + (size_t)row * DMODEL + lane * 2);
    float s  = xv.x + xv.y;
    float ss = xv.x * xv.x + xv.y * xv.y;
    #pragma unroll
    for (int d = 1; d < 64; d <<= 1) {
        s  += __shfl_xor(s, d);
        ss += __shfl_xor(ss, d);
    }
    float mu   = s * (1.0f / 128.0f);
    float var  = ss * (1.0f / 128.0f) - mu * mu;
    float rstd = rsqrtf(var + 1e-5f);
    float2 gv = *(const float2*)(g + lane * 2);
    float2 bv = *(const float2*)(b + lane * 2);
    float2 o;
    o.x = (xv.x - mu) * rstd * gv.x + bv.x;
    o.y = (xv.y - mu) * rstd * gv.y + bv.y;
    *(float2*)(out + (size_t)row * DMODEL + lane * 2) = o;
}

// ---------------------------------------------------------------------------
// Generic fp32 GEMM: C = A[MxK] @ B[KxN] + bias, with epilogue modes:
//   0: + bias                      (QKV projections)
//   1: + bias + R                  (residual adds: Wo, FFN2)
//   2: gelu(+ bias)                (FFN1)
//   3: + bias + R + degs[i]*wdeg[j] + bdeg[j]   (positional encoding; R = xn)
// Tiles: 64x64 output, BK=32, 256 threads, 4x4 micro-tile.
// ---------------------------------------------------------------------------
__global__ __launch_bounds__(256)
void gemm_kernel(const float* __restrict__ A, const float* __restrict__ B,
                 const float* __restrict__ bias, const float* __restrict__ R,
                 const float* __restrict__ degs, const float* __restrict__ wdeg,
                 const float* __restrict__ bdeg,
                 float* __restrict__ C, int M, int N, int K, int mode)
{
    __shared__ float As[32][64];   // As[k][m]
    __shared__ float Bs[32][64];   // Bs[k][n]
    const int tid = threadIdx.x;
    const int tx = tid & 15;       // 0..15 -> 4 cols each
    const int ty = tid >> 4;       // 0..15 -> 4 rows each
    const int br = blockIdx.x * 64;
    const int bc = blockIdx.y * 64;

    float acc[4][4] = {};

    for (int kt = 0; kt < K; kt += 32) {
        // A tile 64 rows x 32 k  (512 float4, 2 per thread), transposed store
        #pragma unroll
        for (int i = 0; i < 2; ++i) {
            int idx  = tid + i * 256;
            int row  = idx >> 3;     // 0..63
            int k4   = idx & 7;      // 0..7
            int grow = br + row;
            float4 av = make_float4(0.f, 0.f, 0.f, 0.f);
            if (grow < M) av = *(const float4*)(A + (size_t)grow * K + kt + k4 * 4);
            As[k4 * 4 + 0][row] = av.x;
            As[k4 * 4 + 1][row] = av.y;
            As[k4 * 4 + 2][row] = av.z;
            As[k4 * 4 + 3][row] = av.w;
        }
        // B tile 32 k x 64 cols (512 float4, 2 per thread), direct store
        #pragma unroll
        for (int i = 0; i < 2; ++i) {
            int idx = tid + i * 256;
            int row = idx >> 4;      // 0..31
            int c4  = idx & 15;      // 0..15
            float4 bv = *(const float4*)(B + (size_t)(kt + row) * N + bc + c4 * 4);
            *(float4*)&Bs[row][c4 * 4] = bv;
        }
        __syncthreads();
        #pragma unroll
        for (int kk = 0; kk < 32; ++kk) {
            float4 a = *(const float4*)&As[kk][ty * 4];
            float4 b = *(const float4*)&Bs[kk][tx * 4];
            acc[0][0] += a.x * b.x; acc[0][1] += a.x * b.y; acc[0][2] += a.x * b.z; acc[0][3] += a.x * b.w;
            acc[1][0] += a.y * b.x; acc[1][1] += a.y * b.y; acc[1][2] += a.y * b.z; acc[1][3] += a.y * b.w;
            acc[2][0] += a.z * b.x; acc[2][1] += a.z * b.y; acc[2][2] += a.z * b.z; acc[2][3] += a.z * b.w;
            acc[3][0] += a.w * b.x; acc[3][1] += a.w * b.y; acc[3][2] += a.w * b.z; acc[3][3] += a.w * b.w;
        }
        __syncthreads();
    }

    #pragma unroll
    for (int r = 0; r < 4; ++r) {
        int row = br + ty * 4 + r;
        if (row >= M) continue;
        #pragma unroll
        for (int c = 0; c < 4; ++c) {
            int col = bc + tx * 4 + c;
            float val = acc[r][c] + bias[col];
            if (mode == 1) {
                val += R[(size_t)row * N + col];
            } else if (mode == 2) {
                val = 0.5f * val * (1.0f + erff(val * 0.70710678118654752f));
            } else if (mode == 3) {
                val += R[(size_t)row * N + col] + degs[row] * wdeg[col] + bdeg[col];
            }
            C[(size_t)row * N + col] = val;
        }
    }
}

// ---------------------------------------------------------------------------
// Degree pipeline
// ---------------------------------------------------------------------------
__global__ void deg_init(float* __restrict__ deg, int n)
{
    int i = blockIdx.x * 256 + threadIdx.x;
    if (i < n) deg[i] = 1.0f;     // self loop
}

__global__ void deg_count(const int* __restrict__ src, float* __restrict__ deg, int e)
{
    int i = blockIdx.x * 256 + threadIdx.x;
    if (i < e) atomicAdd(&deg[src[i]], 1.0f);
}

__global__ __launch_bounds__(256)
void deg_var(const float* __restrict__ deg, float* __restrict__ stats, float mean, int n)
{
    float acc = 0.f;
    for (int i = blockIdx.x * blockDim.x + threadIdx.x; i < n; i += gridDim.x * blockDim.x) {
        float d = deg[i] - mean;
        acc += d * d;
    }
    #pragma unroll
    for (int d = 1; d < 64; d <<= 1) acc += __shfl_xor(acc, d);
    __shared__ float wsum[4];
    int lane = threadIdx.x & 63, wv = threadIdx.x >> 6;
    if (lane == 0) wsum[wv] = acc;
    __syncthreads();
    if (threadIdx.x == 0) atomicAdd(stats, wsum[0] + wsum[1] + wsum[2] + wsum[3]);
}

__global__ void deg_norm(const float* __restrict__ deg, const float* __restrict__ stats,
                         float* __restrict__ degs, float mean, int n)
{
    int i = blockIdx.x * 256 + threadIdx.x;
    if (i >= n) return;
    float sd = sqrtf(stats[0] / (float)(n - 1));
    degs[i] = (deg[i] - mean) / (sd + 1e-6f);
}

// ---------------------------------------------------------------------------
// CSR build (grouped by dst; self loops appended)
// ---------------------------------------------------------------------------
__global__ void csr_count(const int* __restrict__ ei, int* __restrict__ counts, int e, int n)
{
    int i = blockIdx.x * 256 + threadIdx.x;
    if (i >= e + n) return;
    int d = (i < e) ? ei[e + i] : (i - e);
    atomicAdd(&counts[d], 1);
}

__global__ __launch_bounds__(256)
void scan_block(const int* __restrict__ in, int* __restrict__ out,
                int* __restrict__ sums, int n)
{
    __shared__ int buf[2][256];
    int t = threadIdx.x;
    int i = blockIdx.x * 256 + t;
    int v = (i < n) ? in[i] : 0;
    buf[0][t] = v;
    __syncthreads();
    int cur = 0;
    #pragma unroll
    for (int d = 1; d < 256; d <<= 1) {
        int val = buf[cur][t] + ((t >= d) ? buf[cur][t - d] : 0);
        buf[cur ^ 1][t] = val;
        cur ^= 1;
        __syncthreads();
    }
    if (i < n) out[i] = buf[cur][t] - v;   // exclusive
    if (t == 255 && sums) sums[blockIdx.x] = buf[cur][255];
}

__global__ void scan_add(int* __restrict__ offs, const int* __restrict__ carry, int n)
{
    int i = blockIdx.x * 256 + threadIdx.x;
    if (i < n) offs[i] += carry[blockIdx.x];
}

__global__ void csr_fill(const int* __restrict__ ei, const int* __restrict__ offs,
                         int* __restrict__ cursor, int* __restrict__ csr_src, int e, int n)
{
    int i = blockIdx.x * 256 + threadIdx.x;
    if (i >= e + n) return;
    int d, s;
    if (i < e) { s = ei[i]; d = ei[e + i]; }
    else       { s = d = i - e; }
    int pos = offs[d] + atomicAdd(&cursor[d], 1);
    csr_src[pos] = s;
}

// ---------------------------------------------------------------------------
// Attention: one wave per dst node. Lane l holds dims {2l, 2l+1};
// head h = lane>>3 (8 lanes per head, HD=16). Two passes over neighbors:
// pass 1 finds per-head max, pass 2 recomputes logits and accumulates
// exp-weighted V. alpha division distributed to the end.
// ---------------------------------------------------------------------------
__global__ __launch_bounds__(256)
void attn_kernel(const float* __restrict__ q, const float* __restrict__ k,
                 const float* __restrict__ v, const int* __restrict__ csr_src,
                 const int* __restrict__ offs, const int* __restrict__ counts,
                 float* __restrict__ aggr, int n)
{
    int wave = threadIdx.x >> 6;
    int lane = threadIdx.x & 63;
    int node = blockIdx.x * 4 + wave;
    if (node >= n) return;

    float2 qv = *(const float2*)(q + (size_t)node * DMODEL + lane * 2);
    int beg = offs[node];
    int cnt = counts[node];

    float m = -1e30f;
    for (int t = 0; t < cnt; ++t) {
        int j = csr_src[beg + t];
        float2 kv = *(const float2*)(k + (size_t)j * DMODEL + lane * 2);
        float p = qv.x * kv.x + qv.y * kv.y;
        p += __shfl_xor(p, 1);
        p += __shfl_xor(p, 2);
        p += __shfl_xor(p, 4);
        float att = p * 0.25f;                        // / sqrt(16)
        att = (att != att) ? 0.0f : fminf(fmaxf(att, -50.f), 50.f);
        m = fmaxf(m, att);
    }

    float s = 0.f, ax = 0.f, ay = 0.f;
    for (int t = 0; t < cnt; ++t) {
        int j = csr_src[beg + t];
        float2 kv = *(const float2*)(k + (size_t)j * DMODEL + lane * 2);
        float p = qv.x * kv.x + qv.y * kv.y;
        p += __shfl_xor(p, 1);
        p += __shfl_xor(p, 2);
        p += __shfl_xor(p, 4);
        float att = p * 0.25f;
        att = (att != att) ? 0.0f : fminf(fmaxf(att, -50.f), 50.f);
        float ex = __expf(att - m);
        s += ex;
        float2 vv = *(const float2*)(v + (size_t)j * DMODEL + lane * 2);
        ax += ex * vv.x;
        ay += ex * vv.y;
    }
    float r = 1.0f / (s + 1e-16f);
    float2 o; o.x = ax * r; o.y = ay * r;
    *(float2*)(aggr + (size_t)node * DMODEL + lane * 2) = o;
}

// ---------------------------------------------------------------------------
extern "C" void kernel_launch(void* const* d_in, const int* in_sizes, int n_in,
                              void* d_out, int out_size, void* d_ws, size_t ws_size,
                              hipStream_t stream)
{
    const float* x_in  = (const float*)d_in[0];
    const int*   ei    = (const int*)d_in[1];
    const float* Wq    = (const float*)d_in[2];
    const float* Wk    = (const float*)d_in[3];
    const float* Wv    = (const float*)d_in[4];
    const float* Wo    = (const float*)d_in[5];
    const float* Wpos  = (const float*)d_in[6];
    const float* Wdeg  = (const float*)d_in[7];
    const float* W1    = (const float*)d_in[8];
    const float* W2    = (const float*)d_in[9];
    const float* bq    = (const float*)d_in[10];
    const float* bk    = (const float*)d_in[11];
    const float* bv    = (const float*)d_in[12];
    const float* bo    = (const float*)d_in[13];
    const float* bpos  = (const float*)d_in[14];
    const float* bdeg  = (const float*)d_in[15];
    const float* ln1_b = (const float*)d_in[16];
    const float* ln2_b = (const float*)d_in[17];
    const float* b1    = (const float*)d_in[18];
    const float* b2    = (const float*)d_in[19];
    const float* ln1_g = (const float*)d_in[20];
    const float* ln2_g = (const float*)d_in[21];

    const int n   = in_sizes[0] / DMODEL;   // 50000
    const int e   = in_sizes[1] / 2;        // 500000
    const int tot = e + n;

    float* x = (float*)d_out;               // running node features

    // ---- workspace layout (256B-aligned slices) ----
    char* p = (char*)d_ws;
    auto alloc = [&](size_t bytes) -> void* {
        void* r = (void*)p;
        p += (bytes + 255) & ~(size_t)255;
        return r;
    };
    float* deg     = (float*)alloc((size_t)n * 4);
    float* degs    = (float*)alloc((size_t)n * 4);
    float* stats   = (float*)alloc(256);
    int*   counts  = (int*)alloc((size_t)n * 4);
    int*   offs    = (int*)alloc((size_t)n * 4);
    int*   cursor  = (int*)alloc((size_t)n * 4);
    int*   bsums   = (int*)alloc(1024);
    int*   carry   = (int*)alloc(1024);
    int*   csr_src = (int*)alloc((size_t)tot * 4);
    float* xn      = (float*)alloc((size_t)n * DMODEL * 4);
    float* xp      = (float*)alloc((size_t)n * DMODEL * 4);  // reused as aggr
    float* qb      = (float*)alloc((size_t)n * DMODEL * 4);
    float* kb      = (float*)alloc((size_t)n * DMODEL * 4);
    float* vb      = (float*)alloc((size_t)n * DMODEL * 4);
    float* hb      = (float*)alloc((size_t)FFCHUNK * FFDIM * 4);

    const int nb_n = (n + 255) / 256;
    const int nb_e = (e + 255) / 256;
    const int nb_t = (tot + 255) / 256;
    const int nscan = nb_n;

    // ---- init x and setup buffers ----
    hipMemcpyAsync(x, x_in, (size_t)n * DMODEL * 4, hipMemcpyDeviceToDevice, stream);
    hipMemsetAsync(stats, 0, 256, stream);
    hipMemsetAsync(counts, 0, (size_t)n * 4, stream);
    hipMemsetAsync(cursor, 0, (size_t)n * 4, stream);

    // ---- degree (layer-invariant) ----
    const float mean = (float)((double)tot / (double)n);
    deg_init<<<nb_n, 256, 0, stream>>>(deg, n);
    deg_count<<<nb_e, 256, 0, stream>>>(ei, deg, e);
    deg_var<<<196, 256, 0, stream>>>(deg, stats, mean, n);
    deg_norm<<<nb_n, 256, 0, stream>>>(deg, stats, degs, mean, n);

    // ---- CSR by dst (layer-invariant) ----
    csr_count<<<nb_t, 256, 0, stream>>>(ei, counts, e, n);
    scan_block<<<nscan, 256, 0, stream>>>(counts, offs, bsums, n);
    scan_block<<<1, 256, 0, stream>>>(bsums, carry, nullptr, nscan);
    scan_add<<<nscan, 256, 0, stream>>>(offs, carry, n);
    csr_fill<<<nb_t, 256, 0, stream>>>(ei, offs, cursor, csr_src, e, n);

    const dim3 gD((n + 63) / 64, DMODEL / 64);   // N-col=128 GEMMs
    const int ln_grid = (n + 3) / 4;

    for (int l = 0; l < NLAYER; ++l) {
        const size_t DD = (size_t)DMODEL * DMODEL;
        const float* wq   = Wq   + (size_t)l * DD;
        const float* wk   = Wk   + (size_t)l * DD;
        const float* wv   = Wv   + (size_t)l * DD;
        const float* wo   = Wo   + (size_t)l * DD;
        const float* wpos = Wpos + (size_t)l * DD;
        const float* wdeg = Wdeg + (size_t)l * DMODEL;
        const float* w1   = W1   + (size_t)l * DMODEL * FFDIM;
        const float* w2   = W2   + (size_t)l * FFDIM * DMODEL;

        // pre-attention LN
        ln_kernel<<<ln_grid, 256, 0, stream>>>(x, ln1_g + l * DMODEL, ln1_b + l * DMODEL, xn, n);
        // xp = xn + xn@Wpos + bpos + degs*wdeg + bdeg
        gemm_kernel<<<gD, 256, 0, stream>>>(xn, wpos, bpos + l * DMODEL, xn,
                                            degs, wdeg, bdeg + l * DMODEL,
                                            xp, n, DMODEL, DMODEL, 3);
        // QKV
        gemm_kernel<<<gD, 256, 0, stream>>>(xp, wq, bq + l * DMODEL, nullptr, nullptr, nullptr, nullptr,
                                            qb, n, DMODEL, DMODEL, 0);
        gemm_kernel<<<gD, 256, 0, stream>>>(xp, wk, bk + l * DMODEL, nullptr, nullptr, nullptr, nullptr,
                                            kb, n, DMODEL, DMODEL, 0);
        gemm_kernel<<<gD, 256, 0, stream>>>(xp, wv, bv + l * DMODEL, nullptr, nullptr, nullptr, nullptr,
                                            vb, n, DMODEL, DMODEL, 0);
        // attention -> aggr (reuses xp buffer; attn only reads q/k/v)
        attn_kernel<<<ln_grid, 256, 0, stream>>>(qb, kb, vb, csr_src, offs, counts, xp, n);
        // x = x + aggr@Wo + bo
        gemm_kernel<<<gD, 256, 0, stream>>>(xp, wo, bo + l * DMODEL, x, nullptr, nullptr, nullptr,
                                            x, n, DMODEL, DMODEL, 1);
        // FFN: xn2 = LN(x); h = gelu(xn2@W1+b1); x += h@W2+b2 (row-chunked)
        ln_kernel<<<ln_grid, 256, 0, stream>>>(x, ln2_g + l * DMODEL, ln2_b + l * DMODEL, xn, n);
        for (int c = 0; c * FFCHUNK < n; ++c) {
            int r0 = c * FFCHUNK;
            int mc = n - r0; if (mc > FFCHUNK) mc = FFCHUNK;
            dim3 g1((mc + 63) / 64, FFDIM / 64);
            gemm_kernel<<<g1, 256, 0, stream>>>(xn + (size_t)r0 * DMODEL, w1, b1 + l * FFDIM,
                                                nullptr, nullptr, nullptr, nullptr,
                                                hb, mc, FFDIM, DMODEL, 2);
            dim3 g2((mc + 63) / 64, DMODEL / 64);
            gemm_kernel<<<g2, 256, 0, stream>>>(hb, w2, b2 + l * DMODEL,
                                                x + (size_t)r0 * DMODEL, nullptr, nullptr, nullptr,
                                                x + (size_t)r0 * DMODEL, mc, DMODEL, FFDIM, 1);
        }
    }
}

// Round 2
// 911.768 us; speedup vs baseline: 1.7254x; 1.7254x over previous
//
#include <hip/hip_runtime.h>
#include <hip/hip_bf16.h>
#include <math.h>

#define DMODEL 128
#define NHEAD 8
#define HEADD 16
#define NLAYER 2
#define FFDIM 512
#define FFCHUNK 12544   // rows per FFN chunk (multiple of 128)
#define MPAD 50048      // N rounded up to 128

using short8 = __attribute__((ext_vector_type(8))) short;
using f32x4  = __attribute__((ext_vector_type(4))) float;

static __device__ __forceinline__ unsigned short f2bf(float f) {
    __hip_bfloat16 h = __float2bfloat16(f);   // RNE
    return *(unsigned short*)&h;
}
static __device__ __forceinline__ float bf2f(unsigned short u) {
    unsigned int v = ((unsigned int)u) << 16;
    return *(float*)&v;
}

// ---------------------------------------------------------------------------
// LayerNorm: one wave per row of 128; float2 per lane; bf16 output.
// ---------------------------------------------------------------------------
__global__ __launch_bounds__(256)
void ln_kernel(const float* __restrict__ x, const float* __restrict__ g,
               const float* __restrict__ b, unsigned short* __restrict__ out, int n)
{
    int wave = threadIdx.x >> 6;
    int lane = threadIdx.x & 63;
    int row  = blockIdx.x * 4 + wave;
    if (row >= n) return;
    float2 xv = *(const float2*)(x + (size_t)row * DMODEL + lane * 2);
    float s  = xv.x + xv.y;
    float ss = xv.x * xv.x + xv.y * xv.y;
    #pragma unroll
    for (int d = 1; d < 64; d <<= 1) {
        s  += __shfl_xor(s, d);
        ss += __shfl_xor(ss, d);
    }
    float mu   = s * (1.0f / 128.0f);
    float var  = ss * (1.0f / 128.0f) - mu * mu;
    float rstd = rsqrtf(var + 1e-5f);
    float2 gv = *(const float2*)(g + lane * 2);
    float2 bv = *(const float2*)(b + lane * 2);
    ushort2 o;
    o.x = f2bf((xv.x - mu) * rstd * gv.x + bv.x);
    o.y = f2bf((xv.y - mu) * rstd * gv.y + bv.y);
    *(ushort2*)(out + (size_t)row * DMODEL + lane * 2) = o;
}

// ---------------------------------------------------------------------------
// Weight convert + transpose: W[L][K][N] fp32 -> Wt[L][N][K] bf16
// ---------------------------------------------------------------------------
__global__ void wconv(const float* __restrict__ W, unsigned short* __restrict__ Wt,
                      int K, int N, int total)
{
    int i = blockIdx.x * 256 + threadIdx.x;
    if (i >= total) return;
    int kn = K * N;
    int l = i / kn;
    int r = i - l * kn;
    int k = r / N;
    int nn = r - k * N;
    Wt[(size_t)l * kn + (size_t)nn * K + k] = f2bf(W[i]);
}

// ---------------------------------------------------------------------------
// bf16 MFMA GEMM: C = A[MxK] @ B[KxN] + bias, epilogue per MODE:
//   0: out fp32 = acc + bias                     (QKV)
//   1: out fp32 = acc + bias + Rf                (residual adds: Wo, FFN2)
//   2: out bf16 = gelu(acc + bias)               (FFN1)
//   3: out bf16 = acc + bias + Rb + degs[i]*wdeg[j] + bdeg[j]   (pos enc)
// A: bf16 [M x K] row-major (rows padded to 128). Bt: bf16 [N x K] (transposed).
// Block: 256 thr = 4 waves (2x2), tile 128x128, BK=32, wave does 4x4 16x16x32.
// ---------------------------------------------------------------------------
template<int MODE>
__global__ __launch_bounds__(256)
void mfma_gemm(const unsigned short* __restrict__ A, const unsigned short* __restrict__ Bt,
               const float* __restrict__ bias,
               const float* __restrict__ Rf, const unsigned short* __restrict__ Rb,
               const float* __restrict__ degs, const float* __restrict__ wdeg,
               const float* __restrict__ bdeg,
               float* __restrict__ outf, unsigned short* __restrict__ outb,
               int M, int N, int K)
{
    __shared__ __align__(16) unsigned short As[128 * 32];
    __shared__ __align__(16) unsigned short Bs[128 * 32];
    const int tid  = threadIdx.x;
    const int wave = tid >> 6, lane = tid & 63;
    const int wr = wave >> 1, wc = wave & 1;
    const int quad = lane >> 4, l15 = lane & 15;
    const size_t br = (size_t)blockIdx.x * 128;
    const size_t bc = (size_t)blockIdx.y * 128;

    f32x4 acc[4][4] = {};

    for (int kt = 0; kt < K; kt += 32) {
        #pragma unroll
        for (int c = 0; c < 2; ++c) {
            int idx = tid + c * 256;           // 0..511
            int row = idx >> 2;                // 0..127
            int kg  = idx & 3;                 // 0..3
            *(short8*)&As[row * 32 + kg * 8] =
                *(const short8*)(A + (br + row) * (size_t)K + kt + kg * 8);
            *(short8*)&Bs[row * 32 + kg * 8] =
                *(const short8*)(Bt + (bc + row) * (size_t)K + kt + kg * 8);
        }
        __syncthreads();
        short8 af[4], bfr[4];
        #pragma unroll
        for (int i = 0; i < 4; ++i)
            af[i] = *(const short8*)&As[(wr * 64 + i * 16 + l15) * 32 + quad * 8];
        #pragma unroll
        for (int j = 0; j < 4; ++j)
            bfr[j] = *(const short8*)&Bs[(wc * 64 + j * 16 + l15) * 32 + quad * 8];
        #pragma unroll
        for (int i = 0; i < 4; ++i)
            #pragma unroll
            for (int j = 0; j < 4; ++j)
                acc[i][j] = __builtin_amdgcn_mfma_f32_16x16x32_bf16(af[i], bfr[j], acc[i][j], 0, 0, 0);
        __syncthreads();
    }

    // epilogue: D row = quad*4 + reg, col = l15 (verified gfx950 C/D layout)
    #pragma unroll
    for (int i = 0; i < 4; ++i) {
        #pragma unroll
        for (int r = 0; r < 4; ++r) {
            size_t row = br + wr * 64 + i * 16 + quad * 4 + r;
            if (row >= (size_t)M) continue;
            #pragma unroll
            for (int j = 0; j < 4; ++j) {
                size_t col = bc + wc * 64 + j * 16 + l15;
                float val = acc[i][j][r] + bias[col];
                if (MODE == 1) {
                    outf[row * N + col] = val + Rf[row * N + col];
                } else if (MODE == 2) {
                    val = 0.5f * val * (1.0f + erff(val * 0.70710678118654752f));
                    outb[row * N + col] = f2bf(val);
                } else if (MODE == 3) {
                    val += bf2f(Rb[row * N + col]) + degs[row] * wdeg[col] + bdeg[col];
                    outb[row * N + col] = f2bf(val);
                } else {
                    outf[row * N + col] = val;
                }
            }
        }
    }
}

// ---------------------------------------------------------------------------
// Degree pipeline
// ---------------------------------------------------------------------------
__global__ void deg_init(float* __restrict__ deg, int n)
{
    int i = blockIdx.x * 256 + threadIdx.x;
    if (i < n) deg[i] = 1.0f;     // self loop
}

__global__ void deg_count(const int* __restrict__ src, float* __restrict__ deg, int e)
{
    int i = blockIdx.x * 256 + threadIdx.x;
    if (i < e) atomicAdd(&deg[src[i]], 1.0f);
}

__global__ __launch_bounds__(256)
void deg_var(const float* __restrict__ deg, float* __restrict__ stats, float mean, int n)
{
    float acc = 0.f;
    for (int i = blockIdx.x * blockDim.x + threadIdx.x; i < n; i += gridDim.x * blockDim.x) {
        float d = deg[i] - mean;
        acc += d * d;
    }
    #pragma unroll
    for (int d = 1; d < 64; d <<= 1) acc += __shfl_xor(acc, d);
    __shared__ float wsum[4];
    int lane = threadIdx.x & 63, wv = threadIdx.x >> 6;
    if (lane == 0) wsum[wv] = acc;
    __syncthreads();
    if (threadIdx.x == 0) atomicAdd(stats, wsum[0] + wsum[1] + wsum[2] + wsum[3]);
}

__global__ void deg_norm(const float* __restrict__ deg, const float* __restrict__ stats,
                         float* __restrict__ degs, float mean, int n)
{
    int i = blockIdx.x * 256 + threadIdx.x;
    if (i >= n) return;
    float sd = sqrtf(stats[0] / (float)(n - 1));
    degs[i] = (deg[i] - mean) / (sd + 1e-6f);
}

// ---------------------------------------------------------------------------
// CSR build (grouped by dst; self loops appended)
// ---------------------------------------------------------------------------
__global__ void csr_count(const int* __restrict__ ei, int* __restrict__ counts, int e, int n)
{
    int i = blockIdx.x * 256 + threadIdx.x;
    if (i >= e + n) return;
    int d = (i < e) ? ei[e + i] : (i - e);
    atomicAdd(&counts[d], 1);
}

__global__ __launch_bounds__(256)
void scan_block(const int* __restrict__ in, int* __restrict__ out,
                int* __restrict__ sums, int n)
{
    __shared__ int buf[2][256];
    int t = threadIdx.x;
    int i = blockIdx.x * 256 + t;
    int v = (i < n) ? in[i] : 0;
    buf[0][t] = v;
    __syncthreads();
    int cur = 0;
    #pragma unroll
    for (int d = 1; d < 256; d <<= 1) {
        int val = buf[cur][t] + ((t >= d) ? buf[cur][t - d] : 0);
        buf[cur ^ 1][t] = val;
        cur ^= 1;
        __syncthreads();
    }
    if (i < n) out[i] = buf[cur][t] - v;   // exclusive
    if (t == 255 && sums) sums[blockIdx.x] = buf[cur][255];
}

__global__ void scan_add(int* __restrict__ offs, const int* __restrict__ carry, int n)
{
    int i = blockIdx.x * 256 + threadIdx.x;
    if (i < n) offs[i] += carry[blockIdx.x];
}

__global__ void csr_fill(const int* __restrict__ ei, const int* __restrict__ offs,
                         int* __restrict__ cursor, int* __restrict__ csr_src, int e, int n)
{
    int i = blockIdx.x * 256 + threadIdx.x;
    if (i >= e + n) return;
    int d, s;
    if (i < e) { s = ei[i]; d = ei[e + i]; }
    else       { s = d = i - e; }
    int pos = offs[d] + atomicAdd(&cursor[d], 1);
    csr_src[pos] = s;
}

// ---------------------------------------------------------------------------
// Attention: one wave per dst node, single pass, online softmax.
// Lane l holds dims {2l, 2l+1}; head = lane>>3 (8 lanes/head, HD=16).
// Output aggr in bf16 (feeds Wo MFMA GEMM).
// ---------------------------------------------------------------------------
__global__ __launch_bounds__(256)
void attn_kernel(const float* __restrict__ q, const float* __restrict__ k,
                 const float* __restrict__ v, const int* __restrict__ csr_src,
                 const int* __restrict__ offs, const int* __restrict__ counts,
                 unsigned short* __restrict__ aggr, int n)
{
    int wave = threadIdx.x >> 6;
    int lane = threadIdx.x & 63;
    int node = blockIdx.x * 4 + wave;
    if (node >= n) return;

    float2 qv = *(const float2*)(q + (size_t)node * DMODEL + lane * 2);
    int beg = offs[node];
    int cnt = counts[node];

    float m = -1e30f, s = 0.f, ax = 0.f, ay = 0.f;
    for (int t = 0; t < cnt; ++t) {
        int j = csr_src[beg + t];
        float2 kv = *(const float2*)(k + (size_t)j * DMODEL + lane * 2);
        float p = qv.x * kv.x + qv.y * kv.y;
        p += __shfl_xor(p, 1);
        p += __shfl_xor(p, 2);
        p += __shfl_xor(p, 4);
        float att = p * 0.25f;                        // / sqrt(16)
        att = (att != att) ? 0.0f : fminf(fmaxf(att, -50.f), 50.f);
        float nm    = fmaxf(m, att);
        float scale = __expf(m - nm);                  // 0 on first iter
        float ex    = __expf(att - nm);
        float2 vv = *(const float2*)(v + (size_t)j * DMODEL + lane * 2);
        s  = s  * scale + ex;
        ax = ax * scale + ex * vv.x;
        ay = ay * scale + ex * vv.y;
        m = nm;
    }
    float r = 1.0f / (s + 1e-16f);
    ushort2 o;
    o.x = f2bf(ax * r);
    o.y = f2bf(ay * r);
    *(ushort2*)(aggr + (size_t)node * DMODEL + lane * 2) = o;
}

// ---------------------------------------------------------------------------
extern "C" void kernel_launch(void* const* d_in, const int* in_sizes, int n_in,
                              void* d_out, int out_size, void* d_ws, size_t ws_size,
                              hipStream_t stream)
{
    const float* x_in  = (const float*)d_in[0];
    const int*   ei    = (const int*)d_in[1];
    const float* Wq    = (const float*)d_in[2];
    const float* Wk    = (const float*)d_in[3];
    const float* Wv    = (const float*)d_in[4];
    const float* Wo    = (const float*)d_in[5];
    const float* Wpos  = (const float*)d_in[6];
    const float* Wdeg  = (const float*)d_in[7];
    const float* W1    = (const float*)d_in[8];
    const float* W2    = (const float*)d_in[9];
    const float* bq    = (const float*)d_in[10];
    const float* bk    = (const float*)d_in[11];
    const float* bv    = (const float*)d_in[12];
    const float* bo    = (const float*)d_in[13];
    const float* bpos  = (const float*)d_in[14];
    const float* bdeg  = (const float*)d_in[15];
    const float* ln1_b = (const float*)d_in[16];
    const float* ln2_b = (const float*)d_in[17];
    const float* b1    = (const float*)d_in[18];
    const float* b2    = (const float*)d_in[19];
    const float* ln1_g = (const float*)d_in[20];
    const float* ln2_g = (const float*)d_in[21];

    const int n   = in_sizes[0] / DMODEL;   // 50000
    const int e   = in_sizes[1] / 2;        // 500000
    const int tot = e + n;

    float* x = (float*)d_out;               // running node features (fp32)

    // ---- workspace layout (256B-aligned slices) ----
    char* p = (char*)d_ws;
    auto alloc = [&](size_t bytes) -> void* {
        void* r = (void*)p;
        p += (bytes + 255) & ~(size_t)255;
        return r;
    };
    float* deg     = (float*)alloc((size_t)n * 4);
    float* degs    = (float*)alloc((size_t)n * 4);
    float* stats   = (float*)alloc(256);
    int*   counts  = (int*)alloc((size_t)n * 4);
    int*   offs    = (int*)alloc((size_t)n * 4);
    int*   cursor  = (int*)alloc((size_t)n * 4);
    int*   bsums   = (int*)alloc(1024);
    int*   carry   = (int*)alloc(1024);
    int*   csr_src = (int*)alloc((size_t)tot * 4);
    unsigned short* xnb  = (unsigned short*)alloc((size_t)MPAD * DMODEL * 2);
    unsigned short* xp   = (unsigned short*)alloc((size_t)MPAD * DMODEL * 2);
    unsigned short* aggr = (unsigned short*)alloc((size_t)MPAD * DMODEL * 2);
    float* qb      = (float*)alloc((size_t)MPAD * DMODEL * 4);
    float* kb      = (float*)alloc((size_t)MPAD * DMODEL * 4);
    float* vb      = (float*)alloc((size_t)MPAD * DMODEL * 4);
    unsigned short* hb   = (unsigned short*)alloc((size_t)FFCHUNK * FFDIM * 2);
    unsigned short* wqt  = (unsigned short*)alloc((size_t)NLAYER * DMODEL * DMODEL * 2);
    unsigned short* wkt  = (unsigned short*)alloc((size_t)NLAYER * DMODEL * DMODEL * 2);
    unsigned short* wvt  = (unsigned short*)alloc((size_t)NLAYER * DMODEL * DMODEL * 2);
    unsigned short* wot  = (unsigned short*)alloc((size_t)NLAYER * DMODEL * DMODEL * 2);
    unsigned short* wpt  = (unsigned short*)alloc((size_t)NLAYER * DMODEL * DMODEL * 2);
    unsigned short* w1t  = (unsigned short*)alloc((size_t)NLAYER * DMODEL * FFDIM * 2);
    unsigned short* w2t  = (unsigned short*)alloc((size_t)NLAYER * FFDIM * DMODEL * 2);

    const int nb_n = (n + 255) / 256;
    const int nb_e = (e + 255) / 256;
    const int nb_t = (tot + 255) / 256;
    const int nscan = nb_n;

    // ---- init ----
    hipMemcpyAsync(x, x_in, (size_t)n * DMODEL * 4, hipMemcpyDeviceToDevice, stream);
    hipMemsetAsync(stats, 0, 256, stream);
    hipMemsetAsync(counts, 0, (size_t)n * 4, stream);
    hipMemsetAsync(cursor, 0, (size_t)n * 4, stream);

    // ---- weight convert+transpose (bf16 [N][K]) ----
    {
        int tDD = NLAYER * DMODEL * DMODEL;
        int tW1 = NLAYER * DMODEL * FFDIM;
        wconv<<<(tDD + 255) / 256, 256, 0, stream>>>(Wq,   wqt, DMODEL, DMODEL, tDD);
        wconv<<<(tDD + 255) / 256, 256, 0, stream>>>(Wk,   wkt, DMODEL, DMODEL, tDD);
        wconv<<<(tDD + 255) / 256, 256, 0, stream>>>(Wv,   wvt, DMODEL, DMODEL, tDD);
        wconv<<<(tDD + 255) / 256, 256, 0, stream>>>(Wo,   wot, DMODEL, DMODEL, tDD);
        wconv<<<(tDD + 255) / 256, 256, 0, stream>>>(Wpos, wpt, DMODEL, DMODEL, tDD);
        wconv<<<(tW1 + 255) / 256, 256, 0, stream>>>(W1,   w1t, DMODEL, FFDIM,  tW1);
        wconv<<<(tW1 + 255) / 256, 256, 0, stream>>>(W2,   w2t, FFDIM,  DMODEL, tW1);
    }

    // ---- degree (layer-invariant) ----
    const float mean = (float)((double)tot / (double)n);
    deg_init<<<nb_n, 256, 0, stream>>>(deg, n);
    deg_count<<<nb_e, 256, 0, stream>>>(ei, deg, e);
    deg_var<<<196, 256, 0, stream>>>(deg, stats, mean, n);
    deg_norm<<<nb_n, 256, 0, stream>>>(deg, stats, degs, mean, n);

    // ---- CSR by dst (layer-invariant) ----
    csr_count<<<nb_t, 256, 0, stream>>>(ei, counts, e, n);
    scan_block<<<nscan, 256, 0, stream>>>(counts, offs, bsums, n);
    scan_block<<<1, 256, 0, stream>>>(bsums, carry, nullptr, nscan);
    scan_add<<<nscan, 256, 0, stream>>>(offs, carry, n);
    csr_fill<<<nb_t, 256, 0, stream>>>(ei, offs, cursor, csr_src, e, n);

    const dim3 gD((n + 127) / 128, 1);     // N=128 GEMMs over all nodes
    const int ln_grid = (n + 3) / 4;

    for (int l = 0; l < NLAYER; ++l) {
        const size_t DD = (size_t)DMODEL * DMODEL;
        const float* wdeg = Wdeg + (size_t)l * DMODEL;
        const unsigned short* wq   = wqt + l * DD;
        const unsigned short* wk   = wkt + l * DD;
        const unsigned short* wv   = wvt + l * DD;
        const unsigned short* wo   = wot + l * DD;
        const unsigned short* wpos = wpt + l * DD;
        const unsigned short* w1   = w1t + (size_t)l * DMODEL * FFDIM;
        const unsigned short* w2   = w2t + (size_t)l * FFDIM * DMODEL;

        // pre-attention LN -> bf16
        ln_kernel<<<ln_grid, 256, 0, stream>>>(x, ln1_g + l * DMODEL, ln1_b + l * DMODEL, xnb, n);
        // xp = xn + xn@Wpos + bpos + degs*wdeg + bdeg   (bf16 out)
        mfma_gemm<3><<<gD, 256, 0, stream>>>(xnb, wpos, bpos + l * DMODEL,
                                             nullptr, xnb, degs, wdeg, bdeg + l * DMODEL,
                                             nullptr, xp, n, DMODEL, DMODEL);
        // QKV (fp32 out)
        mfma_gemm<0><<<gD, 256, 0, stream>>>(xp, wq, bq + l * DMODEL,
                                             nullptr, nullptr, nullptr, nullptr, nullptr,
                                             qb, nullptr, n, DMODEL, DMODEL);
        mfma_gemm<0><<<gD, 256, 0, stream>>>(xp, wk, bk + l * DMODEL,
                                             nullptr, nullptr, nullptr, nullptr, nullptr,
                                             kb, nullptr, n, DMODEL, DMODEL);
        mfma_gemm<0><<<gD, 256, 0, stream>>>(xp, wv, bv + l * DMODEL,
                                             nullptr, nullptr, nullptr, nullptr, nullptr,
                                             vb, nullptr, n, DMODEL, DMODEL);
        // attention -> aggr (bf16)
        attn_kernel<<<ln_grid, 256, 0, stream>>>(qb, kb, vb, csr_src, offs, counts, aggr, n);
        // x = x + aggr@Wo + bo   (fp32)
        mfma_gemm<1><<<gD, 256, 0, stream>>>(aggr, wo, bo + l * DMODEL,
                                             x, nullptr, nullptr, nullptr, nullptr,
                                             x, nullptr, n, DMODEL, DMODEL);
        // FFN
        ln_kernel<<<ln_grid, 256, 0, stream>>>(x, ln2_g + l * DMODEL, ln2_b + l * DMODEL, xnb, n);
        for (int c = 0; c * FFCHUNK < n; ++c) {
            int r0 = c * FFCHUNK;
            int mc = n - r0; if (mc > FFCHUNK) mc = FFCHUNK;
            dim3 g1((mc + 127) / 128, FFDIM / 128);
            mfma_gemm<2><<<g1, 256, 0, stream>>>(xnb + (size_t)r0 * DMODEL, w1, b1 + l * FFDIM,
                                                 nullptr, nullptr, nullptr, nullptr, nullptr,
                                                 nullptr, hb, mc, FFDIM, DMODEL);
            dim3 g2((mc + 127) / 128, 1);
            mfma_gemm<1><<<g2, 256, 0, stream>>>(hb, w2, b2 + l * DMODEL,
                                                 x + (size_t)r0 * DMODEL, nullptr, nullptr, nullptr, nullptr,
                                                 x + (size_t)r0 * DMODEL, nullptr, mc, DMODEL, FFDIM);
        }
    }
}